// Round 1
// baseline (126.798 us; speedup 1.0000x reference)
//
#include <hip/hip_runtime.h>
#include <hip/hip_bf16.h>
#include <stdint.h>

#define N_NODES 8192
#define DIM 128
#define MASK_WORDS_PER_ROW 256   /* 8192 cols / 32 bits */
#define MASK_U4_PER_ROW 64

// ---------------------------------------------------------------------------
// K2: scatter edges into the adjacency bitmap. atomicOr gives exact
// "duplicates collapse to 1.0" set semantics.
// Handles both int32-converted and raw-int64 edge_index layouts.
// ---------------------------------------------------------------------------
__global__ void edge_scatter(const void* __restrict__ eiv, int E,
                             unsigned int* __restrict__ mask) {
    const int* e32 = (const int*)eiv;
    const long long* e64 = (const long long*)eiv;
    // If the harness passed raw int64 data, reading as int32 gives
    // [lo0, 0, lo1, 0, ...] (all values < 8192 so high words are 0).
    bool is64 = (e32[1] == 0) && (e32[3] == 0) && (e32[5] == 0) &&
                ((e32[0] | e32[2] | e32[4]) != 0);
    int k = blockIdx.x * blockDim.x + threadIdx.x;
    if (k >= E) return;
    int r, c;
    if (is64) {
        r = (int)e64[k];
        c = (int)e64[E + k];
    } else {
        r = e32[k];
        c = e32[E + k];
    }
    if ((unsigned)r < N_NODES && (unsigned)c < N_NODES) {
        atomicOr(&mask[r * MASK_WORDS_PER_ROW + (c >> 5)], 1u << (c & 31));
    }
}

// ---------------------------------------------------------------------------
// K3: degree -> d^{-1/2}. One wave per row: lane popcounts a uint4 (16 B),
// shuffle-reduce over 64 lanes. degree = popcount + 1 (the "+I" term).
// ---------------------------------------------------------------------------
__global__ __launch_bounds__(256) void degree_kernel(
        const unsigned int* __restrict__ mask, float* __restrict__ dinv) {
    int wave = threadIdx.x >> 6;
    int lane = threadIdx.x & 63;
    int row = blockIdx.x * 4 + wave;
    uint4 m = ((const uint4*)mask)[row * MASK_U4_PER_ROW + lane];
    int cnt = __popc(m.x) + __popc(m.y) + __popc(m.z) + __popc(m.w);
    #pragma unroll
    for (int off = 32; off; off >>= 1) cnt += __shfl_down(cnt, off);
    if (lane == 0) dinv[row] = 1.0f / sqrtf((float)(cnt + 1));
}

// ---------------------------------------------------------------------------
// K4: z = x @ W^T   [8192x128] = [8192x128] @ [128x128]^T, fp32.
// Block = 256 thr (4 waves) covers 64 rows x 64 out-cols. lane = row, so
// W accesses are wave-uniform -> compiler emits scalar s_loads; x comes
// from a +1-padded LDS tile (2-way bank aliasing = free on CDNA4).
// ---------------------------------------------------------------------------
__global__ __launch_bounds__(256) void xw_gemm(const float* __restrict__ x,
                                               const float* __restrict__ W,
                                               float* __restrict__ z) {
    __shared__ float xs[64 * 129];
    int b = blockIdx.x;
    int row_tile = b >> 1;           // 0..127
    int do_half = (b & 1) * 64;      // which 64 output cols
    int t = threadIdx.x;
    int row0 = row_tile * 64;

    // Stage 64 rows of x (8192 floats) into padded LDS. float4 global loads
    // (perfectly coalesced), scalar LDS writes into stride-129 layout.
    const float4* xg = (const float4*)(x + (size_t)row0 * DIM);
    for (int i = t; i < 64 * 32; i += 256) {
        float4 v = xg[i];
        int r = i >> 5;
        int din = (i & 31) << 2;
        float* p = &xs[r * 129 + din];
        p[0] = v.x; p[1] = v.y; p[2] = v.z; p[3] = v.w;
    }
    __syncthreads();

    int lane = t & 63;
    int wave = __builtin_amdgcn_readfirstlane(t >> 6);  // force wave-uniform
    int row = row0 + lane;
    const float* xr = &xs[lane * 129];

    #pragma unroll
    for (int p = 0; p < 2; ++p) {
        int dob = do_half + p * 32 + wave * 8;
        float acc[8] = {0.f,0.f,0.f,0.f,0.f,0.f,0.f,0.f};
        for (int din = 0; din < DIM; ++din) {
            float xv = xr[din];
            #pragma unroll
            for (int j = 0; j < 8; ++j)
                acc[j] += xv * W[(dob + j) * DIM + din];  // scalar (uniform)
        }
        float* zp = z + (size_t)row * DIM + dob;
        #pragma unroll
        for (int j = 0; j < 8; ++j) zp[j] = acc[j];
    }
}

// ---------------------------------------------------------------------------
// K5: out[i] = dinv[i] * sum_{bits j} dinv[j]*z[j] + dinv[i]^2*z[i] + b.
// One wave per row. Each lane owns 2 channels (float2, coalesced 512 B/row).
// Mask words are broadcast from each source lane via __shfl (readlane) and
// bits iterated with ffs -> j is wave-uniform -> dinv/z base are scalar.
// ---------------------------------------------------------------------------
__global__ __launch_bounds__(256) void aggregate(
        const unsigned int* __restrict__ mask,
        const float* __restrict__ dinv,
        const float* __restrict__ z,
        const float* __restrict__ bias,
        float* __restrict__ out) {
    int wave = threadIdx.x >> 6;
    int lane = threadIdx.x & 63;
    int row = blockIdx.x * 4 + wave;
    uint4 m = ((const uint4*)mask)[row * MASK_U4_PER_ROW + lane];

    float2 acc = {0.f, 0.f};
    for (int sl = 0; sl < 64; ++sl) {
        unsigned w[4];
        w[0] = (unsigned)__shfl((int)m.x, sl);
        w[1] = (unsigned)__shfl((int)m.y, sl);
        w[2] = (unsigned)__shfl((int)m.z, sl);
        w[3] = (unsigned)__shfl((int)m.w, sl);
        int base = sl * 128;
        #pragma unroll
        for (int c = 0; c < 4; ++c) {
            unsigned wd = w[c];
            int cb = base + c * 32;
            while (wd) {
                int bpos = __ffs(wd) - 1;
                wd &= wd - 1;
                int j = cb + bpos;
                float dj = dinv[j];
                float2 zv = ((const float2*)(z + (size_t)j * DIM))[lane];
                acc.x += dj * zv.x;
                acc.y += dj * zv.y;
            }
        }
    }
    float di = dinv[row];
    float2 zs = ((const float2*)(z + (size_t)row * DIM))[lane];
    float2 bv = ((const float2*)bias)[lane];
    float2 res;
    res.x = di * acc.x + di * di * zs.x + bv.x;
    res.y = di * acc.y + di * di * zs.y + bv.y;
    ((float2*)(out + (size_t)row * DIM))[lane] = res;
}

// ---------------------------------------------------------------------------
extern "C" void kernel_launch(void* const* d_in, const int* in_sizes, int n_in,
                              void* d_out, int out_size, void* d_ws, size_t ws_size,
                              hipStream_t stream) {
    const float* x  = (const float*)d_in[0];
    const void*  ei = d_in[1];
    const float* W  = (const float*)d_in[2];
    const float* bb = (const float*)d_in[3];
    float* out = (float*)d_out;

    uint8_t* ws = (uint8_t*)d_ws;
    unsigned int* mask = (unsigned int*)ws;                       // 8 MB
    float* dinv = (float*)(ws + 8u * 1024u * 1024u);              // 32 KB
    float* z    = (float*)(ws + 8u * 1024u * 1024u + 32u * 1024u);// 4 MB

    int E = in_sizes[1] / 2;

    hipMemsetAsync(mask, 0, N_NODES * MASK_WORDS_PER_ROW * sizeof(unsigned int),
                   stream);
    edge_scatter<<<(E + 255) / 256, 256, 0, stream>>>(ei, E, mask);
    degree_kernel<<<N_NODES / 4, 256, 0, stream>>>(mask, dinv);
    xw_gemm<<<256, 256, 0, stream>>>(x, W, z);
    aggregate<<<N_NODES / 4, 256, 0, stream>>>(mask, dinv, z, bb, out);
}

// Round 2
// 126.109 us; speedup vs baseline: 1.0055x; 1.0055x over previous
//
#include <hip/hip_runtime.h>
#include <hip/hip_bf16.h>
#include <stdint.h>

#define N_NODES 8192
#define DIM 128
#define MASK_WORDS_PER_ROW 256   /* 8192 cols / 32 bits */
#define NBR_STRIDE 512           /* max stored neighbors/row; Poisson(32) => safe */

// ---------------------------------------------------------------------------
// K2: scatter edges. atomicOr on the bitmap gives exact set semantics AND
// tells us (via the returned old value) whether this edge is new -> append
// to a compacted per-row neighbor list. No mask re-scan is ever needed.
// Handles both int32-converted and raw-int64 edge_index layouts.
// ---------------------------------------------------------------------------
__global__ void edge_scatter(const void* __restrict__ eiv, int E,
                             unsigned int* __restrict__ mask,
                             int* __restrict__ cnt,
                             int* __restrict__ nbr) {
    const int* e32 = (const int*)eiv;
    const long long* e64 = (const long long*)eiv;
    bool is64 = (e32[1] == 0) && (e32[3] == 0) && (e32[5] == 0) &&
                ((e32[0] | e32[2] | e32[4]) != 0);
    int k = blockIdx.x * blockDim.x + threadIdx.x;
    if (k >= E) return;
    int r, c;
    if (is64) {
        r = (int)e64[k];
        c = (int)e64[E + k];
    } else {
        r = e32[k];
        c = e32[E + k];
    }
    if ((unsigned)r < N_NODES && (unsigned)c < N_NODES) {
        unsigned bit = 1u << (c & 31);
        unsigned old = atomicOr(&mask[r * MASK_WORDS_PER_ROW + (c >> 5)], bit);
        if (!(old & bit)) {
            int pos = atomicAdd(&cnt[r], 1);
            if (pos < NBR_STRIDE) nbr[r * NBR_STRIDE + pos] = c;
        }
    }
}

// ---------------------------------------------------------------------------
// K3: z = x @ W^T   [8192x128] = [8192x128] @ [128x128]^T, fp32.
// Block = 256 thr (4 waves) covers 64 rows x 64 out-cols. lane = row, so
// W accesses are wave-uniform -> scalar s_loads from K$; x comes from a
// +1-padded LDS tile (2-way bank aliasing = free on CDNA4). Single din
// loop with 16 accumulators (both 32-col halves) to halve LDS reads.
// ---------------------------------------------------------------------------
__global__ __launch_bounds__(256) void xw_gemm(const float* __restrict__ x,
                                               const float* __restrict__ W,
                                               float* __restrict__ z) {
    __shared__ float xs[64 * 129];
    int b = blockIdx.x;
    int row_tile = b >> 1;           // 0..127
    int do_half = (b & 1) * 64;      // which 64 output cols
    int t = threadIdx.x;
    int row0 = row_tile * 64;

    // Stage 64 rows of x into padded LDS (coalesced float4 global loads).
    const float4* xg = (const float4*)(x + (size_t)row0 * DIM);
    for (int i = t; i < 64 * 32; i += 256) {
        float4 v = xg[i];
        int r = i >> 5;
        int din = (i & 31) << 2;
        float* p = &xs[r * 129 + din];
        p[0] = v.x; p[1] = v.y; p[2] = v.z; p[3] = v.w;
    }
    __syncthreads();

    int lane = t & 63;
    int wave = __builtin_amdgcn_readfirstlane(t >> 6);  // force wave-uniform
    int row = row0 + lane;
    const float* xr = &xs[lane * 129];
    int dob = do_half + wave * 8;    // cols [dob,dob+8) and [dob+32,dob+40)

    float acc[16];
    #pragma unroll
    for (int j = 0; j < 16; ++j) acc[j] = 0.f;

    for (int din = 0; din < DIM; ++din) {
        float xv = xr[din];
        #pragma unroll
        for (int j = 0; j < 8; ++j) {
            acc[j]     += xv * W[(dob + j) * DIM + din];
            acc[8 + j] += xv * W[(dob + 32 + j) * DIM + din];
        }
    }
    float* zp = z + (size_t)row * DIM;
    #pragma unroll
    for (int j = 0; j < 8; ++j) {
        zp[dob + j]      = acc[j];
        zp[dob + 32 + j] = acc[8 + j];
    }
}

// ---------------------------------------------------------------------------
// K4: out[i] = di * sum_{j in nbr[i]} dj*z[j] + di^2*z[i] + b,
// di = rsqrt(cnt[i]+1). One wave per row; lane owns 2 channels (float2,
// coalesced 512 B per z-row). Neighbor indices come from the compact list
// (wave-uniform int4 loads) in chunks of 4 -> 4 independent gathers in
// flight to hide L2/L3 latency.
// ---------------------------------------------------------------------------
__global__ __launch_bounds__(256) void aggregate(
        const int* __restrict__ nbr,
        const int* __restrict__ cnt,
        const float* __restrict__ z,
        const float* __restrict__ bias,
        float* __restrict__ out) {
    int wave = threadIdx.x >> 6;
    int lane = threadIdx.x & 63;
    int row = __builtin_amdgcn_readfirstlane(blockIdx.x * 4 + wave);
    int deg = cnt[row];
    const int* lst = nbr + row * NBR_STRIDE;

    float2 acc = {0.f, 0.f};
    int k = 0;
    for (; k + 4 <= deg; k += 4) {
        int4 jj = *(const int4*)(lst + k);
        float w0 = 1.0f / sqrtf((float)(cnt[jj.x] + 1));
        float w1 = 1.0f / sqrtf((float)(cnt[jj.y] + 1));
        float w2 = 1.0f / sqrtf((float)(cnt[jj.z] + 1));
        float w3 = 1.0f / sqrtf((float)(cnt[jj.w] + 1));
        float2 a = ((const float2*)(z + (size_t)jj.x * DIM))[lane];
        float2 b = ((const float2*)(z + (size_t)jj.y * DIM))[lane];
        float2 c = ((const float2*)(z + (size_t)jj.z * DIM))[lane];
        float2 d = ((const float2*)(z + (size_t)jj.w * DIM))[lane];
        acc.x += w0 * a.x + w1 * b.x + w2 * c.x + w3 * d.x;
        acc.y += w0 * a.y + w1 * b.y + w2 * c.y + w3 * d.y;
    }
    for (; k < deg; ++k) {
        int j = lst[k];
        float wj = 1.0f / sqrtf((float)(cnt[j] + 1));
        float2 a = ((const float2*)(z + (size_t)j * DIM))[lane];
        acc.x += wj * a.x;
        acc.y += wj * a.y;
    }

    float di = 1.0f / sqrtf((float)(deg + 1));
    float2 zs = ((const float2*)(z + (size_t)row * DIM))[lane];
    float2 bv = ((const float2*)bias)[lane];
    float2 res;
    res.x = di * acc.x + di * di * zs.x + bv.x;
    res.y = di * acc.y + di * di * zs.y + bv.y;
    ((float2*)(out + (size_t)row * DIM))[lane] = res;
}

// ---------------------------------------------------------------------------
extern "C" void kernel_launch(void* const* d_in, const int* in_sizes, int n_in,
                              void* d_out, int out_size, void* d_ws, size_t ws_size,
                              hipStream_t stream) {
    const float* x  = (const float*)d_in[0];
    const void*  ei = d_in[1];
    const float* W  = (const float*)d_in[2];
    const float* bb = (const float*)d_in[3];
    float* out = (float*)d_out;

    // ws layout: mask 8MB | cnt 32KB | nbr 16MB | z 4MB
    uint8_t* ws = (uint8_t*)d_ws;
    unsigned int* mask = (unsigned int*)ws;
    int* cnt = (int*)(ws + 8u * 1024u * 1024u);
    int* nbr = (int*)(ws + 8u * 1024u * 1024u + 32u * 1024u);
    float* z = (float*)(ws + 24u * 1024u * 1024u + 32u * 1024u);

    int E = in_sizes[1] / 2;

    // Zero mask + cnt in one contiguous memset (they are adjacent).
    hipMemsetAsync(mask, 0,
                   N_NODES * MASK_WORDS_PER_ROW * sizeof(unsigned int)
                   + N_NODES * sizeof(int), stream);
    edge_scatter<<<(E + 255) / 256, 256, 0, stream>>>(ei, E, mask, cnt, nbr);
    xw_gemm<<<256, 256, 0, stream>>>(x, W, z);
    aggregate<<<N_NODES / 4, 256, 0, stream>>>(nbr, cnt, z, bb, out);
}